// Round 15
// baseline (290.958 us; speedup 1.0000x reference)
//
#include <hip/hip_runtime.h>
#include <hip/hip_bf16.h>

#define SEQ 2048
#define QSTR 4096
// (1/sqrt(128)) * log2(e)
#define CSCALE 0.1275174364688796f

typedef __attribute__((ext_vector_type(8)))  short short8;
typedef __attribute__((ext_vector_type(4)))  float f32x4;
typedef __attribute__((ext_vector_type(16))) float f32x16;

union PF8 { unsigned u[4]; short8 s; };

__device__ __forceinline__ unsigned short f2bf(float f) {
    union { __hip_bfloat16 b; unsigned short u; } cv;
    cv.b = __float2bfloat16(f);
    return cv.u;
}
__device__ __forceinline__ float bf2f(unsigned short u) {
    unsigned v = ((unsigned)u) << 16;
    return __builtin_bit_cast(float, v);
}

__device__ __forceinline__ void gload16(const unsigned short* g, unsigned short* l) {
    __builtin_amdgcn_global_load_lds(
        (const __attribute__((address_space(1))) void*)g,
        (__attribute__((address_space(3))) void*)l, 16, 0, 0);
}

// ---- prepass: K -> bf16 [hk][kv][d] ----
__global__ void prep_k(const float* __restrict__ Kg, unsigned short* __restrict__ Kb) {
    int gi = blockIdx.x * 256 + threadIdx.x;
    int kv = gi >> 8;
    int rem = gi & 255;
    int hk = rem >> 5;
    int d4 = rem & 31;
    f32x4 k4 = *(const f32x4*)(Kg + ((size_t)kv * 8 + hk) * 128 + 4 * d4);
    ushort4 u = make_ushort4(f2bf(k4[0]), f2bf(k4[1]), f2bf(k4[2]), f2bf(k4[3]));
    *(ushort4*)(Kb + ((size_t)hk * SEQ + kv) * 128 + 4 * d4) = u;
}

// ---- prepass: V -> bf16 transposed [hk][d][kv] ----
__global__ void prep_v(const float* __restrict__ Vg, unsigned short* __restrict__ Vtb) {
    const int hk  = blockIdx.x >> 5;
    const int kvb = blockIdx.x & 31;
    __shared__ unsigned short T[128][72];
    const int t = threadIdx.x;
    #pragma unroll
    for (int i = 0; i < 8; ++i) {
        int idx = t + 256 * i;
        int r = idx >> 5, d4 = idx & 31;
        f32x4 v = *(const f32x4*)(Vg + ((size_t)(kvb * 64 + r) * 8 + hk) * 128 + 4 * d4);
        T[4 * d4 + 0][r] = f2bf(v[0]);
        T[4 * d4 + 1][r] = f2bf(v[1]);
        T[4 * d4 + 2][r] = f2bf(v[2]);
        T[4 * d4 + 3][r] = f2bf(v[3]);
    }
    __syncthreads();
    #pragma unroll
    for (int i = 0; i < 8; ++i) {
        int idx = t + 256 * i;
        int d = idx >> 4, c4 = idx & 15;
        ushort4 u = *(ushort4*)&T[d][4 * c4];
        *(ushort4*)(Vtb + ((size_t)hk * 128 + d) * SEQ + kvb * 64 + 4 * c4) = u;
    }
}

__launch_bounds__(512, 4)
__global__ void attn_fwd(const float* __restrict__ Qg,
                         const unsigned short* __restrict__ Kb,
                         const unsigned short* __restrict__ Vtb,
                         float* __restrict__ Og) {
    const int bid  = blockIdx.x;           // 512 blocks of 8 waves
    const int half = bid >> 8;
    const int idx  = bid & 255;
    const int jj   = idx >> 4;             // 0..15
    const int j    = half ? jj : 15 - jj;  // superblock (128 q-rows); heavy-first in half 0
    const int h    = (idx & 15) | (half << 4);
    const int hk   = h >> 2;
    const int ns   = 2 * (j + 1);          // KVBLK=64 steps (kv tiles 0..2j+1)

    const int tid  = threadIdx.x;
    const int w    = tid >> 6;             // 0..7
    const int band = w & 3;                // q band (32 rows)
    const int hf   = w >> 2;               // kv half (32 of 64)
    const int lane = tid & 63;
    const int q5   = lane & 31;
    const int t5   = lane >> 5;

    __shared__ unsigned short Ks[2][64][128];   // row-major K, granule ^= (row&15)
    __shared__ unsigned short Vp[2][64][128];   // packed V^T (R10 layout)
    __shared__ float mstat[2][8][32];
    __shared__ unsigned short Otb[32][136];     // bf16 partial-O exchange

    const int q0w = 128 * j + 32 * band;

    // ---- Q fragments (B operand), scale folded ----
    short8 qf[8];
    {
        const float* qp = Qg + (size_t)(q0w + q5) * QSTR + h * 128 + 8 * t5;
        #pragma unroll
        for (int st = 0; st < 8; ++st) {
            f32x4 a = *(const f32x4*)(qp + 16 * st);
            f32x4 c = *(const f32x4*)(qp + 16 * st + 4);
            short8 f;
            f[0] = (short)f2bf(a[0] * CSCALE); f[1] = (short)f2bf(a[1] * CSCALE);
            f[2] = (short)f2bf(a[2] * CSCALE); f[3] = (short)f2bf(a[3] * CSCALE);
            f[4] = (short)f2bf(c[0] * CSCALE); f[5] = (short)f2bf(c[1] * CSCALE);
            f[6] = (short)f2bf(c[2] * CSCALE); f[7] = (short)f2bf(c[3] * CSCALE);
            qf[st] = f;
        }
    }
    #pragma unroll
    for (int st = 0; st < 8; ++st) asm volatile("" :: "v"(qf[st]));
    asm volatile("s_waitcnt vmcnt(0)" ::: "memory");   // drain Q loads: vmcnt counting exact

    // 8-wave staging: wave w covers rows 8w..8w+7 (2 instr K + 2 instr V)
    auto ISSUE = [&](int kv0, int bb) __attribute__((always_inline)) {
        #pragma unroll
        for (int p4 = 0; p4 < 2; ++p4) {
            int row = 8 * w + 4 * p4 + (lane >> 4);
            const unsigned short* g = Kb +
                ((size_t)hk * SEQ + kv0 + row) * 128 + 8 * ((lane & 15) ^ (row & 15));
            gload16(g, &Ks[bb][8 * w + 4 * p4][0]);
        }
        #pragma unroll
        for (int p4 = 0; p4 < 2; ++p4) {
            int r  = 8 * w + 4 * p4 + (lane >> 4);
            int gg = lane & 15;
            int d  = 2 * r + (gg >> 3);
            int c  = (gg & 7) ^ (r & 7);
            const unsigned short* g = Vtb +
                ((size_t)hk * 128 + d) * SEQ + kv0 + 8 * c;
            gload16(g, &Vp[bb][8 * w + 4 * p4][0]);
        }
    };

    f32x16 oacc[4];
    #pragma unroll
    for (int dt = 0; dt < 4; ++dt)
        #pragma unroll
        for (int r = 0; r < 16; ++r) oacc[dt][r] = 0.f;
    float m = -1e30f, l = 0.f;

    ISSUE(0, 0);
    if (ns > 1) ISSUE(64, 1);

    for (int s = 0; s < ns; ++s) {
        const int kv0 = 64 * s;
        const int buf = s & 1;
        if (s + 1 < ns) asm volatile("s_waitcnt vmcnt(4)" ::: "memory");
        else            asm volatile("s_waitcnt vmcnt(0)" ::: "memory");
        __builtin_amdgcn_s_barrier();

        const int kvh = kv0 + 32 * hf;
        if (kvh <= q0w + 31) {
            // ---- S^T = K Q^T ----
            short8 kreg[8];
            #pragma unroll
            for (int st = 0; st < 8; ++st)
                kreg[st] = *(const short8*)
                    &Ks[buf][32 * hf + q5][8 * ((2 * st + t5) ^ (q5 & 15))];
            f32x16 sac;
            #pragma unroll
            for (int r = 0; r < 16; ++r) sac[r] = 0.f;
            __builtin_amdgcn_s_setprio(1);
            #pragma unroll
            for (int st = 0; st < 8; ++st)
                sac = __builtin_amdgcn_mfma_f32_32x32x16_bf16(kreg[st], qf[st], sac, 0, 0, 0);
            __builtin_amdgcn_s_setprio(0);

            // ---- mask (diagonal only) ----
            if (kvh + 31 > q0w) {
                const int qrow = q0w + q5;
                #pragma unroll
                for (int r = 0; r < 16; ++r) {
                    int kv = kvh + (r & 3) + 8 * (r >> 2) + 4 * t5;
                    if (kv > qrow) sac[r] = -1e30f;
                }
            }

            // ---- row max: depth-4 tree + one cross-lane ----
            float m8[8], m4[4], m2[2];
            #pragma unroll
            for (int i = 0; i < 8; ++i) m8[i] = fmaxf(sac[i], sac[i + 8]);
            #pragma unroll
            for (int i = 0; i < 4; ++i) m4[i] = fmaxf(m8[i], m8[i + 4]);
            m2[0] = fmaxf(m4[0], m4[2]); m2[1] = fmaxf(m4[1], m4[3]);
            float mx = fmaxf(m2[0], m2[1]);
            mx = fmaxf(mx, __shfl_xor(mx, 32));

            // ---- defer-max (T13) ----
            const bool skip = __all(mx <= m + 11.0f);
            float fac = 1.0f;
            if (!skip) {
                float mn = fmaxf(m, mx);
                fac = exp2f(m - mn);
                m = mn;
            }

            // ---- P = 2^(S-m); depth-4 tree sum ----
            #pragma unroll
            for (int r = 0; r < 16; ++r) sac[r] = exp2f(sac[r] - m);
            float s8[8], s4[4], s2[2];
            #pragma unroll
            for (int i = 0; i < 8; ++i) s8[i] = sac[i] + sac[i + 8];
            #pragma unroll
            for (int i = 0; i < 4; ++i) s4[i] = s8[i] + s8[i + 4];
            s2[0] = s4[0] + s4[2]; s2[1] = s4[1] + s4[3];
            float ps = s2[0] + s2[1];
            ps += __shfl_xor(ps, 32);
            if (!skip) {
                l = l * fac + ps;
                #pragma unroll
                for (int dt = 0; dt < 4; ++dt)
                    #pragma unroll
                    for (int r = 0; r < 16; ++r) oacc[dt][r] *= fac;
            } else {
                l += ps;
            }

            // ---- pack P pairs to bf16x2 ----
            unsigned pkw[8];
            #pragma unroll
            for (int rp = 0; rp < 8; ++rp)
                pkw[rp] = (unsigned)f2bf(sac[2 * rp]) |
                          ((unsigned)f2bf(sac[2 * rp + 1]) << 16);

            // ---- redistribute to PV B-fragments (cross-half only) ----
            unsigned xp[8];
            #pragma unroll
            for (int i = 0; i < 8; ++i)
                xp[i] = (unsigned)__shfl_xor((int)pkw[i], 32);

            PF8 pf[2];
            #pragma unroll
            for (int ks = 0; ks < 2; ++ks) {
                #pragma unroll
                for (int jq = 0; jq < 4; ++jq) {
                    const int ib = (jq & 1) + 4 * ks;
                    const unsigned own_lo = pkw[ib];
                    const unsigned own_hi = pkw[ib + 2];
                    const unsigned par_lo = xp[ib];
                    const unsigned par_hi = xp[ib + 2];
                    pf[ks].u[jq] = (jq < 2) ? (t5 ? par_hi : own_lo)
                                            : (t5 ? own_hi : par_lo);
                }
            }

            // ---- O^T += V^T P (packed-V read) ----
            __builtin_amdgcn_s_setprio(1);
            #pragma unroll
            for (int dt = 0; dt < 4; ++dt) {
                #pragma unroll
                for (int ks = 0; ks < 2; ++ks) {
                    const int gg = 8 * (q5 & 1) +
                        ((4 * hf + 2 * ks + t5) ^ ((q5 >> 1) & 7));
                    short8 vf = *(const short8*)
                        &Vp[buf][16 * dt + (q5 >> 1)][8 * gg];
                    oacc[dt] = __builtin_amdgcn_mfma_f32_32x32x16_bf16(vf, pf[ks].s, oacc[dt], 0, 0, 0);
                }
            }
            __builtin_amdgcn_s_setprio(0);
        }

        asm volatile("" ::: "memory");
        __builtin_amdgcn_s_barrier();
        if (s + 2 < ns) ISSUE(64 * (s + 2), s & 1);
    }

    // ---- EPI: kv-half combine (w <-> w^4) + 4 band-turns, coalesced store ----
    if (t5 == 0) mstat[0][w][q5] = m;
    asm volatile("s_waitcnt lgkmcnt(0)" ::: "memory");
    __builtin_amdgcn_sched_barrier(0);
    __builtin_amdgcn_s_barrier();
    const float mo = mstat[0][w ^ 4][q5];
    const float M  = fmaxf(m, mo);
    const float sc = exp2f(m - M);
    #pragma unroll
    for (int dt = 0; dt < 4; ++dt)
        #pragma unroll
        for (int r = 0; r < 16; ++r) oacc[dt][r] *= sc;
    const float lp = l * sc;
    if (t5 == 0) mstat[1][w][q5] = lp;
    asm volatile("s_waitcnt lgkmcnt(0)" ::: "memory");
    __builtin_amdgcn_sched_barrier(0);
    __builtin_amdgcn_s_barrier();
    const float rl = 1.0f / (lp + mstat[1][w ^ 4][q5]);

    #pragma unroll 1
    for (int tq = 0; tq < 4; ++tq) {
        if (w == tq + 4) {            // hf==1 wave of band tq: publish partial
            #pragma unroll
            for (int dt = 0; dt < 4; ++dt)
                #pragma unroll
                for (int ii = 0; ii < 4; ++ii) {
                    ushort4 u = make_ushort4(
                        f2bf(oacc[dt][4 * ii + 0]), f2bf(oacc[dt][4 * ii + 1]),
                        f2bf(oacc[dt][4 * ii + 2]), f2bf(oacc[dt][4 * ii + 3]));
                    *(ushort4*)&Otb[q5][32 * dt + 8 * ii + 4 * t5] = u;
                }
        }
        asm volatile("s_waitcnt lgkmcnt(0)" ::: "memory");
        __builtin_amdgcn_sched_barrier(0);
        __builtin_amdgcn_s_barrier();
        if (w == tq) {                // hf==0 wave: combine + normalize
            #pragma unroll
            for (int dt = 0; dt < 4; ++dt)
                #pragma unroll
                for (int ii = 0; ii < 4; ++ii) {
                    ushort4 o1 = *(ushort4*)&Otb[q5][32 * dt + 8 * ii + 4 * t5];
                    ushort4 u = make_ushort4(
                        f2bf((oacc[dt][4 * ii + 0] + bf2f(o1.x)) * rl),
                        f2bf((oacc[dt][4 * ii + 1] + bf2f(o1.y)) * rl),
                        f2bf((oacc[dt][4 * ii + 2] + bf2f(o1.z)) * rl),
                        f2bf((oacc[dt][4 * ii + 3] + bf2f(o1.w)) * rl));
                    *(ushort4*)&Otb[q5][32 * dt + 8 * ii + 4 * t5] = u;
                }
        }
        asm volatile("s_waitcnt lgkmcnt(0)" ::: "memory");
        __builtin_amdgcn_sched_barrier(0);
        __builtin_amdgcn_s_barrier();
        {   // all 512 threads: coalesced fp32 store of band tq rows
            float* ob = Og + (size_t)(128 * j + 32 * tq) * QSTR + h * 128;
            #pragma unroll
            for (int i = 0; i < 2; ++i) {
                int u  = tid + 512 * i;          // 0..1023
                int r  = u >> 5;
                int c4 = (u & 31) * 4;
                ushort4 ub = *(ushort4*)&Otb[r][c4];
                f32x4 v;
                v[0] = bf2f(ub.x); v[1] = bf2f(ub.y);
                v[2] = bf2f(ub.z); v[3] = bf2f(ub.w);
                *(f32x4*)(ob + (size_t)r * QSTR + c4) = v;
            }
        }
        asm volatile("s_waitcnt lgkmcnt(0)" ::: "memory");
        __builtin_amdgcn_sched_barrier(0);
        __builtin_amdgcn_s_barrier();
    }
}

extern "C" void kernel_launch(void* const* d_in, const int* in_sizes, int n_in,
                              void* d_out, int out_size, void* d_ws, size_t ws_size,
                              hipStream_t stream) {
    const float* q = (const float*)d_in[0];
    const float* k = (const float*)d_in[1];
    const float* v = (const float*)d_in[2];
    float* out = (float*)d_out;
    unsigned short* Kb  = (unsigned short*)d_ws;                 // 4 MB
    unsigned short* Vtb = Kb + (size_t)8 * SEQ * 128;            // 4 MB
    prep_k<<<dim3(2048), 256, 0, stream>>>(k, Kb);
    prep_v<<<dim3(256), 256, 0, stream>>>(v, Vtb);
    attn_fwd<<<dim3(512), 512, 0, stream>>>(q, Kb, Vtb, out);
}

// Round 16
// 99.896 us; speedup vs baseline: 2.9126x; 2.9126x over previous
//
#include <hip/hip_runtime.h>
#include <hip/hip_bf16.h>

#define SEQ 2048
#define QSTR 4096
// (1/sqrt(128)) * log2(e)
#define CSCALE 0.1275174364688796f

typedef __attribute__((ext_vector_type(8)))  short short8;
typedef __attribute__((ext_vector_type(4)))  float f32x4;

union PF8 { unsigned u[4]; short8 s; };

__device__ __forceinline__ unsigned short f2bf(float f) {
    union { __hip_bfloat16 b; unsigned short u; } cv;
    cv.b = __float2bfloat16(f);
    return cv.u;
}
__device__ __forceinline__ float bf2f(unsigned short u) {
    unsigned v = ((unsigned)u) << 16;
    return __builtin_bit_cast(float, v);
}

__device__ __forceinline__ void gload16(const unsigned short* g, unsigned short* l) {
    __builtin_amdgcn_global_load_lds(
        (const __attribute__((address_space(1))) void*)g,
        (__attribute__((address_space(3))) void*)l, 16, 0, 0);
}

// ---- prepass: K -> bf16 [hk][kv][d] ----
__global__ void prep_k(const float* __restrict__ Kg, unsigned short* __restrict__ Kb) {
    int gi = blockIdx.x * 256 + threadIdx.x;
    int kv = gi >> 8;
    int rem = gi & 255;
    int hk = rem >> 5;
    int d4 = rem & 31;
    f32x4 k4 = *(const f32x4*)(Kg + ((size_t)kv * 8 + hk) * 128 + 4 * d4);
    ushort4 u = make_ushort4(f2bf(k4[0]), f2bf(k4[1]), f2bf(k4[2]), f2bf(k4[3]));
    *(ushort4*)(Kb + ((size_t)hk * SEQ + kv) * 128 + 4 * d4) = u;
}

// ---- prepass: V -> bf16 transposed [hk][d][kv] ----
__global__ void prep_v(const float* __restrict__ Vg, unsigned short* __restrict__ Vtb) {
    const int hk  = blockIdx.x >> 5;
    const int kvb = blockIdx.x & 31;
    __shared__ unsigned short T[128][72];
    const int t = threadIdx.x;
    #pragma unroll
    for (int i = 0; i < 8; ++i) {
        int idx = t + 256 * i;
        int r = idx >> 5, d4 = idx & 31;
        f32x4 v = *(const f32x4*)(Vg + ((size_t)(kvb * 64 + r) * 8 + hk) * 128 + 4 * d4);
        T[4 * d4 + 0][r] = f2bf(v[0]);
        T[4 * d4 + 1][r] = f2bf(v[1]);
        T[4 * d4 + 2][r] = f2bf(v[2]);
        T[4 * d4 + 3][r] = f2bf(v[3]);
    }
    __syncthreads();
    #pragma unroll
    for (int i = 0; i < 8; ++i) {
        int idx = t + 256 * i;
        int d = idx >> 4, c4 = idx & 15;
        ushort4 u = *(ushort4*)&T[d][4 * c4];
        *(ushort4*)(Vtb + ((size_t)hk * 128 + d) * SEQ + kvb * 64 + 4 * c4) = u;
    }
}

__launch_bounds__(256, 2)
__global__ void attn_fwd(const float* __restrict__ Qg,
                         const unsigned short* __restrict__ Kb,
                         const unsigned short* __restrict__ Vtb,
                         float* __restrict__ Og) {
    const int bid = blockIdx.x;            // 512 blocks, all EXACTLY 33 steps
    const int p   = bid >> 5;              // 0..15
    const int h   = bid & 31;
    const int hk  = h >> 2;
    const int qbB = 31 - p;                // big 64-row q-block (phase B, first)
    const int qbA = p;                     // small (phase A)
    const int nsB = 32 - p;                // B steps; nsB + (p+1) == 33

    const int tid  = threadIdx.x;
    const int w    = tid >> 6;             // 0..3
    const int b    = w & 1;                // q band (32 rows)
    const int hf   = w >> 1;               // kv half (32 of 64)
    const int lane = tid & 63;
    const int c16  = lane & 15;
    const int g    = lane >> 4;            // 0..3

    __shared__ unsigned short Ks[2][64][128];
    __shared__ unsigned short Vp[2][64][128];
    __shared__ float mstat[2][4][32];
    __shared__ unsigned short Otb[32][136];   // bf16 partial-O exchange

    // qf[hf2][kt]: B-frag for q rows 16*hf2 + c16, k elems 32*kt + 8*g + i
    short8 qf[2][4];
    auto LOADQ = [&](int qb) __attribute__((always_inline)) {
        #pragma unroll
        for (int hf2 = 0; hf2 < 2; ++hf2) {
            const float* qp = Qg + (size_t)(qb * 64 + 32 * b + 16 * hf2 + c16) * QSTR
                              + h * 128 + 8 * g;
            #pragma unroll
            for (int kt = 0; kt < 4; ++kt) {
                f32x4 a = *(const f32x4*)(qp + 32 * kt);
                f32x4 c = *(const f32x4*)(qp + 32 * kt + 4);
                short8 f;
                f[0] = (short)f2bf(a[0] * CSCALE); f[1] = (short)f2bf(a[1] * CSCALE);
                f[2] = (short)f2bf(a[2] * CSCALE); f[3] = (short)f2bf(a[3] * CSCALE);
                f[4] = (short)f2bf(c[0] * CSCALE); f[5] = (short)f2bf(c[1] * CSCALE);
                f[6] = (short)f2bf(c[2] * CSCALE); f[7] = (short)f2bf(c[3] * CSCALE);
                qf[hf2][kt] = f;
            }
        }
    };

    auto ISSUE = [&](int kv0, int bb) __attribute__((always_inline)) {
        #pragma unroll
        for (int p4 = 0; p4 < 4; ++p4) {
            int row = 16 * w + 4 * p4 + (lane >> 4);
            const unsigned short* gp = Kb +
                ((size_t)hk * SEQ + kv0 + row) * 128 + 8 * ((lane & 15) ^ (row & 15));
            gload16(gp, &Ks[bb][16 * w + 4 * p4][0]);
        }
        #pragma unroll
        for (int p4 = 0; p4 < 4; ++p4) {
            int r  = 16 * w + 4 * p4 + (lane >> 4);
            int gg = lane & 15;
            int d  = 2 * r + (gg >> 3);
            int c  = (gg & 7) ^ (r & 7);
            const unsigned short* gp = Vtb +
                ((size_t)hk * 128 + d) * SEQ + kv0 + 8 * c;
            gload16(gp, &Vp[bb][16 * w + 4 * p4][0]);
        }
    };

    f32x4 o4[2][8];                        // [hf2][dt]: O^T[16dt+4g+r][16hf2+c16]
    float m[2], l[2];
    auto RESET = [&]() __attribute__((always_inline)) {
        #pragma unroll
        for (int hf2 = 0; hf2 < 2; ++hf2)
            #pragma unroll
            for (int dt = 0; dt < 8; ++dt)
                o4[hf2][dt] = (f32x4){0.f, 0.f, 0.f, 0.f};
        m[0] = m[1] = -1e30f; l[0] = l[1] = 0.f;
    };

    // phase-end: 2-way kv-half combine + coalesced store
    auto EPI = [&](int qb) __attribute__((always_inline)) {
        if (g == 0) { mstat[0][w][c16] = m[0]; mstat[0][w][16 + c16] = m[1]; }
        asm volatile("s_waitcnt lgkmcnt(0)" ::: "memory");
        __builtin_amdgcn_sched_barrier(0);
        __builtin_amdgcn_s_barrier();
        float lp[2], rl[2];
        #pragma unroll
        for (int hf2 = 0; hf2 < 2; ++hf2) {
            const float mo = mstat[0][w ^ 2][16 * hf2 + c16];
            const float M  = fmaxf(m[hf2], mo);
            const float sc = exp2f(m[hf2] - M);
            #pragma unroll
            for (int dt = 0; dt < 8; ++dt)
                #pragma unroll
                for (int r = 0; r < 4; ++r) o4[hf2][dt][r] *= sc;
            lp[hf2] = l[hf2] * sc;
        }
        if (g == 0) { mstat[1][w][c16] = lp[0]; mstat[1][w][16 + c16] = lp[1]; }
        asm volatile("s_waitcnt lgkmcnt(0)" ::: "memory");
        __builtin_amdgcn_sched_barrier(0);
        __builtin_amdgcn_s_barrier();
        #pragma unroll
        for (int hf2 = 0; hf2 < 2; ++hf2)
            rl[hf2] = 1.0f / (lp[hf2] + mstat[1][w ^ 2][16 * hf2 + c16]);

        #pragma unroll 1
        for (int bb = 0; bb < 2; ++bb) {
            if (w == 2 + bb) {            // kv-half-1 wave of band bb: publish partial
                #pragma unroll
                for (int hf2 = 0; hf2 < 2; ++hf2)
                    #pragma unroll
                    for (int dt = 0; dt < 8; ++dt) {
                        ushort4 u = make_ushort4(
                            f2bf(o4[hf2][dt][0]), f2bf(o4[hf2][dt][1]),
                            f2bf(o4[hf2][dt][2]), f2bf(o4[hf2][dt][3]));
                        *(ushort4*)&Otb[16 * hf2 + c16][16 * dt + 4 * g] = u;
                    }
            }
            asm volatile("s_waitcnt lgkmcnt(0)" ::: "memory");
            __builtin_amdgcn_sched_barrier(0);
            __builtin_amdgcn_s_barrier();
            if (w == bb) {                // kv-half-0 wave: combine + normalize
                #pragma unroll
                for (int hf2 = 0; hf2 < 2; ++hf2)
                    #pragma unroll
                    for (int dt = 0; dt < 8; ++dt) {
                        ushort4 o1 = *(ushort4*)&Otb[16 * hf2 + c16][16 * dt + 4 * g];
                        ushort4 u = make_ushort4(
                            f2bf((o4[hf2][dt][0] + bf2f(o1.x)) * rl[hf2]),
                            f2bf((o4[hf2][dt][1] + bf2f(o1.y)) * rl[hf2]),
                            f2bf((o4[hf2][dt][2] + bf2f(o1.z)) * rl[hf2]),
                            f2bf((o4[hf2][dt][3] + bf2f(o1.w)) * rl[hf2]));
                        *(ushort4*)&Otb[16 * hf2 + c16][16 * dt + 4 * g] = u;
                    }
            }
            asm volatile("s_waitcnt lgkmcnt(0)" ::: "memory");
            __builtin_amdgcn_sched_barrier(0);
            __builtin_amdgcn_s_barrier();
            {   // all 256 threads: coalesced fp32 store of band bb rows
                const int r  = tid >> 3;
                const int c0 = 16 * (tid & 7);
                float* og = Og + (size_t)(qb * 64 + 32 * bb + r) * QSTR + h * 128 + c0;
                #pragma unroll
                for (int j = 0; j < 4; ++j) {
                    ushort4 u = *(ushort4*)&Otb[r][c0 + 4 * j];
                    f32x4 v;
                    v[0] = bf2f(u.x); v[1] = bf2f(u.y);
                    v[2] = bf2f(u.z); v[3] = bf2f(u.w);
                    *(f32x4*)(og + 4 * j) = v;
                }
            }
            asm volatile("s_waitcnt lgkmcnt(0)" ::: "memory");
            __builtin_amdgcn_sched_barrier(0);
            __builtin_amdgcn_s_barrier();
        }
    };

    LOADQ(qbB);
    #pragma unroll
    for (int hf2 = 0; hf2 < 2; ++hf2)
        #pragma unroll
        for (int kt = 0; kt < 4; ++kt) asm volatile("" :: "v"(qf[hf2][kt]));
    asm volatile("s_waitcnt vmcnt(0)" ::: "memory");
    RESET();

    ISSUE(0, 0);
    ISSUE(64, 1);

    for (int s = 0; s < 33; ++s) {
        if (s == nsB) {              // phase switch B -> A
            LOADQ(qbA);              // hides under EPI (vmcnt over-wait once: safe)
            EPI(qbB);
            RESET();
        }
        const bool isB = (s < nsB);
        const int kv0  = isB ? 64 * s : 64 * (s - nsB);
        const int qb   = isB ? qbB : qbA;
        const int q0w  = qb * 64 + 32 * b;
        const int buf  = s & 1;

        if (s + 1 < 33) asm volatile("s_waitcnt vmcnt(8)" ::: "memory");
        else            asm volatile("s_waitcnt vmcnt(0)" ::: "memory");
        __builtin_amdgcn_s_barrier();

        const int kvh = kv0 + 32 * hf;        // this wave's 32-kv chunk base
        if (kvh <= q0w + 31) {
            // ---- K fragments (shared by both q-halves) ----
            short8 kf[8];                     // [ct*4 + kt]
            #pragma unroll
            for (int ct = 0; ct < 2; ++ct)
                #pragma unroll
                for (int kt = 0; kt < 4; ++kt)
                    kf[4 * ct + kt] = *(const short8*)
                        &Ks[buf][32 * hf + 16 * ct + c16][8 * ((4 * kt + g) ^ c16)];

            // ---- S^T: 4 independent depth-4 MFMA chains ----
            f32x4 sac[2][2];                  // [hf2][ct]
            #pragma unroll
            for (int hf2 = 0; hf2 < 2; ++hf2)
                #pragma unroll
                for (int ct = 0; ct < 2; ++ct)
                    sac[hf2][ct] = (f32x4){0.f, 0.f, 0.f, 0.f};
            __builtin_amdgcn_s_setprio(1);
            #pragma unroll
            for (int kt = 0; kt < 4; ++kt) {
                sac[0][0] = __builtin_amdgcn_mfma_f32_16x16x32_bf16(kf[kt],     qf[0][kt], sac[0][0], 0, 0, 0);
                sac[1][0] = __builtin_amdgcn_mfma_f32_16x16x32_bf16(kf[kt],     qf[1][kt], sac[1][0], 0, 0, 0);
                sac[0][1] = __builtin_amdgcn_mfma_f32_16x16x32_bf16(kf[4 + kt], qf[0][kt], sac[0][1], 0, 0, 0);
                sac[1][1] = __builtin_amdgcn_mfma_f32_16x16x32_bf16(kf[4 + kt], qf[1][kt], sac[1][1], 0, 0, 0);
            }
            __builtin_amdgcn_s_setprio(0);

            // ---- mask (diagonal only): kv = kvh+16ct+4g+r vs qrow = q0w+16hf2+c16
            if (kvh + 31 > q0w) {
                #pragma unroll
                for (int hf2 = 0; hf2 < 2; ++hf2) {
                    const int qrow = q0w + 16 * hf2 + c16;
                    #pragma unroll
                    for (int ct = 0; ct < 2; ++ct)
                        #pragma unroll
                        for (int r = 0; r < 4; ++r) {
                            int kv = kvh + 16 * ct + 4 * g + r;
                            if (kv > qrow) sac[hf2][ct][r] = -1e30f;
                        }
                }
            }

            // ---- per-half row max: in-lane depth-3 + 2 shuffles (2 indep chains)
            float mx[2];
            #pragma unroll
            for (int hf2 = 0; hf2 < 2; ++hf2) {
                float t4a = fmaxf(sac[hf2][0][0], sac[hf2][1][0]);
                float t4b = fmaxf(sac[hf2][0][1], sac[hf2][1][1]);
                float t4c = fmaxf(sac[hf2][0][2], sac[hf2][1][2]);
                float t4d = fmaxf(sac[hf2][0][3], sac[hf2][1][3]);
                float t2a = fmaxf(t4a, t4b), t2b = fmaxf(t4c, t4d);
                float mm = fmaxf(t2a, t2b);
                mm = fmaxf(mm, __shfl_xor(mm, 16));
                mm = fmaxf(mm, __shfl_xor(mm, 32));
                mx[hf2] = mm;
            }

            // ---- defer-max (T13), joint over halves ----
            const bool skip = __all(fmaxf(mx[0] - m[0], mx[1] - m[1]) <= 11.0f);
            if (!skip) {
                #pragma unroll
                for (int hf2 = 0; hf2 < 2; ++hf2) {
                    float mn  = fmaxf(m[hf2], mx[hf2]);
                    float fac = exp2f(m[hf2] - mn);
                    m[hf2] = mn;
                    l[hf2] *= fac;
                    #pragma unroll
                    for (int dt = 0; dt < 8; ++dt)
                        #pragma unroll
                        for (int r = 0; r < 4; ++r) o4[hf2][dt][r] *= fac;
                }
            }

            // ---- P = 2^(S-m); per-half sum; pack to bf16x2 ----
            unsigned pk[2][4];                // [hf2][2ct+pp]
            #pragma unroll
            for (int hf2 = 0; hf2 < 2; ++hf2) {
                #pragma unroll
                for (int ct = 0; ct < 2; ++ct)
                    #pragma unroll
                    for (int r = 0; r < 4; ++r)
                        sac[hf2][ct][r] = exp2f(sac[hf2][ct][r] - m[hf2]);
                float s4a = sac[hf2][0][0] + sac[hf2][1][0];
                float s4b = sac[hf2][0][1] + sac[hf2][1][1];
                float s4c = sac[hf2][0][2] + sac[hf2][1][2];
                float s4d = sac[hf2][0][3] + sac[hf2][1][3];
                float ps = (s4a + s4b) + (s4c + s4d);
                ps += __shfl_xor(ps, 16);
                ps += __shfl_xor(ps, 32);
                l[hf2] += ps;
                #pragma unroll
                for (int ct = 0; ct < 2; ++ct)
                    #pragma unroll
                    for (int pp = 0; pp < 2; ++pp)
                        pk[hf2][2 * ct + pp] =
                            (unsigned)f2bf(sac[hf2][ct][2 * pp]) |
                            ((unsigned)f2bf(sac[hf2][ct][2 * pp + 1]) << 16);
            }

            // ---- redistribute to PV B-fragments ----
            // pf[hf2].u[w4] = P[8g+2w4 .. +1][16hf2+c16], from lane
            // (c16, 2(g&1)+(w4>>1)) register pk[2*(g>>1) + (w4&1)]
            PF8 pf0, pf1;
            {
                const int sel = g >> 1;
                #pragma unroll
                for (int w4 = 0; w4 < 4; ++w4) {
                    const int src = 16 * (2 * (g & 1) + (w4 >> 1)) + c16;
                    unsigned lo0 = (unsigned)__shfl((int)pk[0][w4 & 1], src);
                    unsigned hi0 = (unsigned)__shfl((int)pk[0][2 + (w4 & 1)], src);
                    unsigned lo1 = (unsigned)__shfl((int)pk[1][w4 & 1], src);
                    unsigned hi1 = (unsigned)__shfl((int)pk[1][2 + (w4 & 1)], src);
                    pf0.u[w4] = sel ? hi0 : lo0;
                    pf1.u[w4] = sel ? hi1 : lo1;
                }
            }

            // ---- O^T += V^T P: shared vf, 2 independent accumulator sets ----
            __builtin_amdgcn_s_setprio(1);
            #pragma unroll
            for (int dt = 0; dt < 8; ++dt) {
                const int gg = 8 * (c16 & 1) + ((4 * hf + g) ^ (c16 >> 1));
                short8 vf = *(const short8*)&Vp[buf][8 * dt + (c16 >> 1)][8 * gg];
                o4[0][dt] = __builtin_amdgcn_mfma_f32_16x16x32_bf16(vf, pf0.s, o4[0][dt], 0, 0, 0);
                o4[1][dt] = __builtin_amdgcn_mfma_f32_16x16x32_bf16(vf, pf1.s, o4[1][dt], 0, 0, 0);
            }
            __builtin_amdgcn_s_setprio(0);
        }

        asm volatile("" ::: "memory");
        __builtin_amdgcn_s_barrier();
        if (s + 2 < 33) {
            const int s2 = s + 2;
            ISSUE((s2 < nsB) ? 64 * s2 : 64 * (s2 - nsB), s & 1);
        }
    }

    EPI(qbA);
}

extern "C" void kernel_launch(void* const* d_in, const int* in_sizes, int n_in,
                              void* d_out, int out_size, void* d_ws, size_t ws_size,
                              hipStream_t stream) {
    const float* q = (const float*)d_in[0];
    const float* k = (const float*)d_in[1];
    const float* v = (const float*)d_in[2];
    float* out = (float*)d_out;
    unsigned short* Kb  = (unsigned short*)d_ws;                 // 4 MB
    unsigned short* Vtb = Kb + (size_t)8 * SEQ * 128;            // 4 MB
    prep_k<<<dim3(2048), 256, 0, stream>>>(k, Kb);
    prep_v<<<dim3(256), 256, 0, stream>>>(v, Vtb);
    attn_fwd<<<dim3(512), 256, 0, stream>>>(q, Kb, Vtb, out);
}

// Round 17
// 87.154 us; speedup vs baseline: 3.3384x; 1.1462x over previous
//
#include <hip/hip_runtime.h>
#include <hip/hip_bf16.h>

#define SEQ 2048
#define QSTR 4096
// (1/sqrt(128)) * log2(e)
#define CSCALE 0.1275174364688796f

typedef __attribute__((ext_vector_type(8)))  short short8;
typedef __attribute__((ext_vector_type(4)))  float f32x4;
typedef __attribute__((ext_vector_type(16))) float f32x16;

union PF8 { unsigned u[4]; short8 s; };

__device__ __forceinline__ unsigned short f2bf(float f) {
    union { __hip_bfloat16 b; unsigned short u; } cv;
    cv.b = __float2bfloat16(f);
    return cv.u;
}

__device__ __forceinline__ void gload16(const unsigned short* g, unsigned short* l) {
    __builtin_amdgcn_global_load_lds(
        (const __attribute__((address_space(1))) void*)g,
        (__attribute__((address_space(3))) void*)l, 16, 0, 0);
}

// ---- prepass: K -> bf16 [hk][kv][d] ----
__global__ void prep_k(const float* __restrict__ Kg, unsigned short* __restrict__ Kb) {
    int gi = blockIdx.x * 256 + threadIdx.x;
    int kv = gi >> 8;
    int rem = gi & 255;
    int hk = rem >> 5;
    int d4 = rem & 31;
    f32x4 k4 = *(const f32x4*)(Kg + ((size_t)kv * 8 + hk) * 128 + 4 * d4);
    ushort4 u = make_ushort4(f2bf(k4[0]), f2bf(k4[1]), f2bf(k4[2]), f2bf(k4[3]));
    *(ushort4*)(Kb + ((size_t)hk * SEQ + kv) * 128 + 4 * d4) = u;
}

// ---- prepass: V -> bf16 transposed [hk][d][kv] ----
__global__ void prep_v(const float* __restrict__ Vg, unsigned short* __restrict__ Vtb) {
    const int hk  = blockIdx.x >> 5;
    const int kvb = blockIdx.x & 31;
    __shared__ unsigned short T[128][72];
    const int t = threadIdx.x;
    #pragma unroll
    for (int i = 0; i < 8; ++i) {
        int idx = t + 256 * i;
        int r = idx >> 5, d4 = idx & 31;
        f32x4 v = *(const f32x4*)(Vg + ((size_t)(kvb * 64 + r) * 8 + hk) * 128 + 4 * d4);
        T[4 * d4 + 0][r] = f2bf(v[0]);
        T[4 * d4 + 1][r] = f2bf(v[1]);
        T[4 * d4 + 2][r] = f2bf(v[2]);
        T[4 * d4 + 3][r] = f2bf(v[3]);
    }
    __syncthreads();
    #pragma unroll
    for (int i = 0; i < 8; ++i) {
        int idx = t + 256 * i;
        int d = idx >> 4, c4 = idx & 15;
        ushort4 u = *(ushort4*)&T[d][4 * c4];
        *(ushort4*)(Vtb + ((size_t)hk * 128 + d) * SEQ + kvb * 64 + 4 * c4) = u;
    }
}

__launch_bounds__(512, 2)
__global__ void attn_fwd(const float* __restrict__ Qg,
                         const unsigned short* __restrict__ Kb,
                         const unsigned short* __restrict__ Vtb,
                         float* __restrict__ Og) {
    const int bid = blockIdx.x;            // 256 blocks, 1 per CU (LDS-capped)
    const int pr  = bid >> 5;              // 0..7 pair index
    const int h   = bid & 31;
    const int hk  = h >> 2;
    const int QBb = 15 - pr;               // big superblock (rows 128*QBb..+127)
    const int QBa = pr;                    // small superblock
    const int nsB = QBb + 1;               // 9..16; nsB + (QBa+1) == 17

    const int tid  = threadIdx.x;
    const int w    = tid >> 6;             // 0..7
    const int wq   = w & 3;                // q band
    const int wk   = w >> 2;               // kv half
    const int lane = tid & 63;
    const int q5   = lane & 31;
    const int t5   = lane >> 5;

    __shared__ __align__(16) unsigned char smem[150016];
    typedef unsigned short TileT[128][128];
    TileT* Ks = (TileT*)smem;                           // 2 x 32 KB, 4-bit XOR swizzle
    TileT* Vt = (TileT*)(smem + 65536);                 // 2 x 32 KB, packed-V layout
    float* mlm = (float*)(smem + 131072);               // [8][32]
    float* mll = (float*)(smem + 132096);               // [8][32]
    float (*Ot)[132] = (float(*)[132])(smem + 133120);  // [32][132] transpose scratch

    // ---- Q fragments (working set; reloaded at phase switch) ----
    short8 qf[8];
    auto LOADQ = [&](int QB) __attribute__((always_inline)) {
        const float* qp = Qg + (size_t)(QB * 128 + 32 * wq + q5) * QSTR + h * 128 + 8 * t5;
        #pragma unroll
        for (int st = 0; st < 8; ++st) {
            f32x4 a = *(const f32x4*)(qp + 16 * st);
            f32x4 b = *(const f32x4*)(qp + 16 * st + 4);
            short8 f;
            f[0] = (short)f2bf(a[0] * CSCALE); f[1] = (short)f2bf(a[1] * CSCALE);
            f[2] = (short)f2bf(a[2] * CSCALE); f[3] = (short)f2bf(a[3] * CSCALE);
            f[4] = (short)f2bf(b[0] * CSCALE); f[5] = (short)f2bf(b[1] * CSCALE);
            f[6] = (short)f2bf(b[2] * CSCALE); f[7] = (short)f2bf(b[3] * CSCALE);
            qf[st] = f;
        }
    };

    auto ISSUE = [&](int kv0, int b) __attribute__((always_inline)) {
        // K: linear LDS dest, 4-bit inverse-swizzled source (2-way max on read)
        #pragma unroll
        for (int p4 = 0; p4 < 4; ++p4) {
            int row = 16 * w + 4 * p4 + (lane >> 4);
            const unsigned short* g = Kb +
                ((size_t)hk * SEQ + kv0 + row) * 128 + 8 * ((lane & 15) ^ (row & 15));
            gload16(g, &Ks[b][16 * w + 4 * p4][0]);
        }
        // V packed: LDS row16 = 64*hh + r holds d = 2r+(gg>>3), kv-granule (gg&7)^(r&7)
        #pragma unroll
        for (int p4 = 0; p4 < 4; ++p4) {
            int row16 = 16 * w + 4 * p4 + (lane >> 4);   // 0..127
            int hh = row16 >> 6, r = row16 & 63;
            int gg = lane & 15;
            int d  = 2 * r + (gg >> 3);
            int c  = (gg & 7) ^ (r & 7);
            const unsigned short* g = Vtb +
                ((size_t)hk * 128 + d) * SEQ + kv0 + 64 * hh + 8 * c;
            gload16(g, &Vt[b][16 * w + 4 * p4][0]);
        }
    };

    f32x16 oacc[4];
    float m, l;
    auto RESET = [&]() __attribute__((always_inline)) {
        #pragma unroll
        for (int dt = 0; dt < 4; ++dt)
            #pragma unroll
            for (int r = 0; r < 16; ++r) oacc[dt][r] = 0.f;
        m = -1e30f; l = 0.f;
    };

    // phase-end: combine kv-half partials (flash-decoding algebra) + store
    auto EPI = [&](int QBp) __attribute__((always_inline)) {
        if (t5 == 0) mlm[w * 32 + q5] = m;
        asm volatile("s_waitcnt lgkmcnt(0)" ::: "memory");
        __builtin_amdgcn_sched_barrier(0);
        __builtin_amdgcn_s_barrier();
        const float mOth = mlm[(w ^ 4) * 32 + q5];
        const float M  = fmaxf(m, mOth);
        const float sc = exp2f(m - M);
        const float lp = l * sc;
        #pragma unroll
        for (int dt = 0; dt < 4; ++dt)
            #pragma unroll
            for (int r = 0; r < 16; ++r) oacc[dt][r] *= sc;
        if (t5 == 0) mll[w * 32 + q5] = lp;
        asm volatile("s_waitcnt lgkmcnt(0)" ::: "memory");
        __builtin_amdgcn_sched_barrier(0);
        __builtin_amdgcn_s_barrier();
        const float lOth = mll[(w ^ 4) * 32 + q5];

        #pragma unroll 1
        for (int tq = 0; tq < 4; ++tq) {
            if (w == tq + 4) {            // kv-half-1 wave of band tq: publish partial
                #pragma unroll
                for (int dt = 0; dt < 4; ++dt)
                    #pragma unroll
                    for (int b = 0; b < 4; ++b) {
                        f32x4 v;
                        v[0] = oacc[dt][4 * b + 0]; v[1] = oacc[dt][4 * b + 1];
                        v[2] = oacc[dt][4 * b + 2]; v[3] = oacc[dt][4 * b + 3];
                        *(f32x4*)&Ot[q5][32 * dt + 8 * b + 4 * t5] = v;
                    }
            }
            asm volatile("s_waitcnt lgkmcnt(0)" ::: "memory");
            __builtin_amdgcn_sched_barrier(0);
            __builtin_amdgcn_s_barrier();
            if (w == tq) {                // kv-half-0 wave: combine + normalize
                const float rl = 1.0f / (lp + lOth);
                #pragma unroll
                for (int dt = 0; dt < 4; ++dt)
                    #pragma unroll
                    for (int b = 0; b < 4; ++b) {
                        f32x4 o1 = *(const f32x4*)&Ot[q5][32 * dt + 8 * b + 4 * t5];
                        f32x4 oc;
                        oc[0] = (oacc[dt][4 * b + 0] + o1[0]) * rl;
                        oc[1] = (oacc[dt][4 * b + 1] + o1[1]) * rl;
                        oc[2] = (oacc[dt][4 * b + 2] + o1[2]) * rl;
                        oc[3] = (oacc[dt][4 * b + 3] + o1[3]) * rl;
                        *(f32x4*)&Ot[q5][32 * dt + 8 * b + 4 * t5] = oc;
                    }
            }
            asm volatile("s_waitcnt lgkmcnt(0)" ::: "memory");
            __builtin_amdgcn_sched_barrier(0);
            __builtin_amdgcn_s_barrier();
            {   // all 512 threads: coalesced store of rows 128*QBp + 32*tq ..+31
                float* ob = Og + (size_t)(QBp * 128 + 32 * tq) * QSTR + h * 128;
                #pragma unroll
                for (int i = 0; i < 2; ++i) {
                    int u  = tid + 512 * i;        // 0..1023
                    int r  = u >> 5;
                    int c4 = (u & 31) * 4;
                    f32x4 v = *(const f32x4*)&Ot[r][c4];
                    *(f32x4*)(ob + (size_t)r * QSTR + c4) = v;
                }
            }
            asm volatile("s_waitcnt lgkmcnt(0)" ::: "memory");
            __builtin_amdgcn_sched_barrier(0);
            __builtin_amdgcn_s_barrier();
        }
    };

    LOADQ(QBb);
    #pragma unroll
    for (int st = 0; st < 8; ++st) asm volatile("" :: "v"(qf[st]));
    asm volatile("s_waitcnt vmcnt(0)" ::: "memory");
    RESET();

    ISSUE(0, 0);
    ISSUE(128, 1);    // nsB >= 9, so step 1 is always a B tile

    for (int s = 0; s < 17; ++s) {
        if (s == nsB) {               // phase switch: B done -> A
            LOADQ(QBa);               // flies during EPI
            EPI(QBb);
            RESET();
        }
        const bool isB = (s < nsB);
        const int kv0   = isB ? 128 * s : 128 * (s - nsB);
        const int q0blk = isB ? 128 * QBb : 128 * QBa;
        const int buf = s & 1;

        if (s + 1 < 17) asm volatile("s_waitcnt vmcnt(8)" ::: "memory");
        else            asm volatile("s_waitcnt vmcnt(0)" ::: "memory");
        __builtin_amdgcn_s_barrier();

        const int q0w = q0blk + 32 * wq;
        const int kvb = kv0 + 64 * wk;         // this wave's kv-half base
        if (kvb <= q0w + 31) {
            // ---- S^T = K Q^T on own kv-half ----
            f32x16 sac[2];
            __builtin_amdgcn_s_setprio(1);
            #pragma unroll
            for (int kvs = 0; kvs < 2; ++kvs) {
                f32x16 acc;
                #pragma unroll
                for (int r = 0; r < 16; ++r) acc[r] = 0.f;
                #pragma unroll
                for (int st = 0; st < 8; ++st) {
                    short8 kf = *(const short8*)
                        &Ks[buf][64 * wk + 32 * kvs + q5][8 * ((2 * st + t5) ^ (q5 & 15))];
                    acc = __builtin_amdgcn_mfma_f32_32x32x16_bf16(kf, qf[st], acc, 0, 0, 0);
                }
                sac[kvs] = acc;
            }
            __builtin_amdgcn_s_setprio(0);

            // ---- mask (diagonal only) ----
            if (kvb + 63 > q0w) {
                const int qrow = q0w + q5;
                #pragma unroll
                for (int kvs = 0; kvs < 2; ++kvs)
                    #pragma unroll
                    for (int r = 0; r < 16; ++r) {
                        int kv = kvb + 32 * kvs + (r & 3) + 8 * (r >> 2) + 4 * t5;
                        if (kv > qrow) sac[kvs][r] = -1e30f;
                    }
            }

            // ---- row max: depth-5 tree + one cross-lane ----
            float t16[16], t8[8], t4[4], t2[2];
            #pragma unroll
            for (int i = 0; i < 16; ++i) t16[i] = fmaxf(sac[0][i], sac[1][i]);
            #pragma unroll
            for (int i = 0; i < 8; ++i) t8[i] = fmaxf(t16[i], t16[i + 8]);
            #pragma unroll
            for (int i = 0; i < 4; ++i) t4[i] = fmaxf(t8[i], t8[i + 4]);
            t2[0] = fmaxf(t4[0], t4[2]); t2[1] = fmaxf(t4[1], t4[3]);
            float mx = fmaxf(t2[0], t2[1]);
            mx = fmaxf(mx, __shfl_xor(mx, 32));

            // ---- defer-max (T13) ----
            const bool skip = __all(mx <= m + 11.0f);
            float fac = 1.0f;
            if (!skip) {
                float mn = fmaxf(m, mx);
                fac = exp2f(m - mn);
                m = mn;
            }

            // ---- P = 2^(S-m); depth-5 tree sum ----
            float ps;
            {
                #pragma unroll
                for (int kvs = 0; kvs < 2; ++kvs)
                    #pragma unroll
                    for (int r = 0; r < 16; ++r)
                        sac[kvs][r] = exp2f(sac[kvs][r] - m);
                float s16[16], s8[8], s4[4], s2[2];
                #pragma unroll
                for (int i = 0; i < 16; ++i) s16[i] = sac[0][i] + sac[1][i];
                #pragma unroll
                for (int i = 0; i < 8; ++i) s8[i] = s16[i] + s16[i + 8];
                #pragma unroll
                for (int i = 0; i < 4; ++i) s4[i] = s8[i] + s8[i + 4];
                s2[0] = s4[0] + s4[2]; s2[1] = s4[1] + s4[3];
                ps = s2[0] + s2[1];
                ps += __shfl_xor(ps, 32);
            }
            if (!skip) {
                l = l * fac + ps;
                #pragma unroll
                for (int dt = 0; dt < 4; ++dt)
                    #pragma unroll
                    for (int r = 0; r < 16; ++r) oacc[dt][r] *= fac;
            } else {
                l += ps;
            }

            // ---- pack P pairs to bf16x2 ----
            unsigned pkw[2][8];
            #pragma unroll
            for (int a = 0; a < 2; ++a)
                #pragma unroll
                for (int rp = 0; rp < 8; ++rp)
                    pkw[a][rp] = (unsigned)f2bf(sac[a][2 * rp]) |
                                 ((unsigned)f2bf(sac[a][2 * rp + 1]) << 16);

            // ---- redistribute: 8 shfl (half of before) via t5-preselected send ----
            // t5=0 sends its hi regs {2,3,6,7}, needs partner lo {0,1,4,5}; t5=1 vice versa.
            unsigned rcv[2][4];
            #pragma unroll
            for (int a = 0; a < 2; ++a)
                #pragma unroll
                for (int i = 0; i < 4; ++i) {
                    const int loI = (i & 1) + 4 * (i >> 1);       // {0,1,4,5}
                    const int hiI = loI + 2;                      // {2,3,6,7}
                    unsigned wsend = t5 ? pkw[a][loI] : pkw[a][hiI];
                    rcv[a][i] = (unsigned)__shfl_xor((int)wsend, 32);
                }

            PF8 pf[4];
            #pragma unroll
            for (int ks = 0; ks < 4; ++ks) {
                const int a = ks >> 1;
                #pragma unroll
                for (int j = 0; j < 4; ++j) {
                    const int ib = (j & 1) + 4 * (ks & 1);
                    const int ri = (j & 1) + 2 * (ks & 1);        // recv index
                    const unsigned own_lo = pkw[a][ib];
                    const unsigned own_hi = pkw[a][ib + 2];
                    const unsigned par    = rcv[a][ri];
                    pf[ks].u[j] = (j < 2) ? (t5 ? par : own_lo)
                                          : (t5 ? own_hi : par);
                }
            }

            // ---- O^T += V^T P (packed-V read: 2-way max banks) ----
            __builtin_amdgcn_s_setprio(1);
            #pragma unroll
            for (int dt = 0; dt < 4; ++dt) {
                #pragma unroll
                for (int ks = 0; ks < 4; ++ks) {
                    const int gg = 8 * (q5 & 1) +
                        ((2 * ks + t5) ^ ((q5 >> 1) & 7));
                    short8 vf = *(const short8*)
                        &Vt[buf][64 * wk + 16 * dt + (q5 >> 1)][8 * gg];
                    oacc[dt] = __builtin_amdgcn_mfma_f32_32x32x16_bf16(vf, pf[ks].s, oacc[dt], 0, 0, 0);
                }
            }
            __builtin_amdgcn_s_setprio(0);
        }

        asm volatile("" ::: "memory");
        __builtin_amdgcn_s_barrier();
        if (s + 2 < 17) {
            const int s2 = s + 2;
            ISSUE((s2 < nsB) ? 128 * s2 : 128 * (s2 - nsB), s & 1);
        }
    }

    EPI(QBa);
}

extern "C" void kernel_launch(void* const* d_in, const int* in_sizes, int n_in,
                              void* d_out, int out_size, void* d_ws, size_t ws_size,
                              hipStream_t stream) {
    const float* q = (const float*)d_in[0];
    const float* k = (const float*)d_in[1];
    const float* v = (const float*)d_in[2];
    float* out = (float*)d_out;
    unsigned short* Kb  = (unsigned short*)d_ws;                 // 4 MB
    unsigned short* Vtb = Kb + (size_t)8 * SEQ * 128;            // 4 MB
    prep_k<<<dim3(2048), 256, 0, stream>>>(k, Kb);
    prep_v<<<dim3(256), 256, 0, stream>>>(v, Vtb);
    attn_fwd<<<dim3(256), 512, 0, stream>>>(q, Kb, Vtb, out);
}